// Round 1
// 15.128 us; speedup vs baseline: 1.0996x; 1.0996x over previous
//
#include <hip/hip_runtime.h>

// out[b,f,o,r] = log( sum_cin softmax(logits)[o,cin,ki,kj,r] * exp(ll[b,f,cin,r]) )
// ki = (f>>5)&3, kj = f&3.  B=128, F=1024, CIN=16, COUT=16, K=4, R=2.
//
// v2: quarter-row-per-thread (4x wave count), coalesced LDS staging of
// exp(ll), per-block softmax of only the 8 needed kk slices, conflict-free
// LDS layouts, dense float4 stores.
//
// LDS weight layout: swW[kkloc*520 + ci*32 + o*2 + r]   (520 = 512+8 pad)
//   -> inner-loop read (ci*32 term == 0 mod 32 banks) is one aligned float4
//      {o_r0, o_r1, o+1_r0, o+1_r1}; lane banks = 8*kkloc + 4*q (2-way max).
// LDS E layout:      swE[row*36 + ci*2 + r]             (36 = 32+4 pad)
//   -> row bank offset 4, 16 rows/wave x 4-lane broadcast: 2-way max.

#define WSTRIDE 520
#define ESTRIDE 36

__global__ __launch_bounds__(256, 4) void sumconv_fused(
    const float* __restrict__ ll, const float* __restrict__ logits,
    float* __restrict__ out) {
  __shared__ float sw[8 * WSTRIDE + 64 * ESTRIDE];  // 25,856 B -> 6 blocks/CU
  float* __restrict__ swW = sw;
  float* __restrict__ swE = sw + 8 * WSTRIDE;

  const int tid = threadIdx.x;
  const int blk = blockIdx.x;
  const int f_base = (blk * 64) & 1023;         // tile spans f in [f_base, f_base+64)
  const int kkbase = ((f_base >> 5) & 3) * 4;   // even (f>>5)&3  -> kkbase in {0, 8}

  // ---- prologue A: softmax of the 8 kk slices this tile needs (1 per thread) ----
  {
    const int r = tid & 1, kkloc = (tid >> 1) & 7, o = tid >> 4;
    const int kk = kkbase + kkloc;
    // logits float index: ((o*16+ci)*16+kk)*2 + r = o*512 + ci*32 + kk*2 + r
    const float* __restrict__ lg = logits + o * 512 + kk * 2 + r;
    float v[16];
    float m = -1e30f;
#pragma unroll
    for (int ci = 0; ci < 16; ++ci) {
      v[ci] = lg[ci * 32];
      m = fmaxf(m, v[ci]);
    }
    float sum = 0.f;
#pragma unroll
    for (int ci = 0; ci < 16; ++ci) {
      v[ci] = __expf(v[ci] - m);
      sum += v[ci];
    }
    const float inv = 1.0f / sum;
#pragma unroll
    for (int ci = 0; ci < 16; ++ci)
      swW[kkloc * WSTRIDE + ci * 32 + o * 2 + r] = v[ci] * inv;
  }

  // ---- prologue B: stage exp(ll) for 64 rows, fully coalesced (1 KiB/instr) ----
  {
    const float4* __restrict__ src = (const float4*)(ll + (size_t)blk * 2048);
#pragma unroll
    for (int j = 0; j < 2; ++j) {
      const int p = tid + 256 * j;       // float4 index within tile (0..511)
      const float4 v = src[p];
      const int row = p >> 3, c4 = p & 7;
      *(float4*)(swE + row * ESTRIDE + c4 * 4) =
          make_float4(__expf(v.x), __expf(v.y), __expf(v.z), __expf(v.w));
    }
  }
  __syncthreads();

  // ---- main: thread (row, q) computes o in {2q, 2q+1, 2q+8, 2q+9} ----
  const int row = tid >> 2, q = tid & 3;
  const int i = blk * 64 + row;                  // global (b,f) row
  const int f = i & 1023;
  const int kk = (((f >> 5) & 3) << 2) | (f & 3);
  const float* __restrict__ wb = swW + (kk & 7) * WSTRIDE + q * 4;
  const float* __restrict__ eb = swE + row * ESTRIDE;

  float Ef[32];
#pragma unroll
  for (int k = 0; k < 8; ++k)
    *(float4*)(Ef + 4 * k) = *(const float4*)(eb + 4 * k);

  float4* __restrict__ op = (float4*)(out + (size_t)i * 32);
#pragma unroll 1  // bound register pressure: one o-pair's weights in flight
  for (int oo = 0; oo < 2; ++oo) {
    float a00 = 0.f, a01 = 0.f, a10 = 0.f, a11 = 0.f;
#pragma unroll
    for (int ci = 0; ci < 16; ++ci) {
      const float4 w = *(const float4*)(wb + ci * 32 + oo * 16);
      a00 = fmaf(w.x, Ef[2 * ci + 0], a00);
      a01 = fmaf(w.y, Ef[2 * ci + 1], a01);
      a10 = fmaf(w.z, Ef[2 * ci + 0], a10);
      a11 = fmaf(w.w, Ef[2 * ci + 1], a11);
    }
    // o-pair (2q+8oo, 2q+8oo+1) -> output float4 #(q + 4*oo) of the row
    op[q + 4 * oo] = make_float4(__logf(a00), __logf(a01), __logf(a10), __logf(a11));
  }
}

extern "C" void kernel_launch(void* const* d_in, const int* in_sizes, int n_in,
                              void* d_out, int out_size, void* d_ws, size_t ws_size,
                              hipStream_t stream) {
  const float* ll     = (const float*)d_in[0];
  const float* logits = (const float*)d_in[1];
  float* out = (float*)d_out;
  // 131072 rows * 4 threads/row / 256 threads/block = 2048 blocks
  sumconv_fused<<<2048, 256, 0, stream>>>(ll, logits, out);
}

// Round 2
// 14.070 us; speedup vs baseline: 1.1823x; 1.0752x over previous
//
#include <hip/hip_runtime.h>

// out[b,f,o,r] = log( sum_cin softmax(logits)[o,cin,ki,kj,r] * exp(ll[b,f,cin,r]) )
// ki = (f>>5)&3, kj = f&3.  B=128, F=1024, CIN=16, COUT=16, K=4, R=2.
//
// v3: 4 rows per thread (4 consecutive b, same f => identical kk slice), so
// each 16B weight ds_read_b128 feeds 16 FMAs instead of 4. Per-row LDS b128
// reads drop 40 -> 16 (the v2 bottleneck: ~6.4us/CU of LDS reads -> ~2.9us).
// Block = 64 f x 4 b = 256 rows; 512 blocks x 256 threads; 53.5 KB LDS
// (2 blocks/CU). All LDS access patterns <=2-way aliased (free per m136).

#define WSTRIDE 520  // 512 + 8: kkloc bank offset 8, q offset 4 -> 2-way max
#define ESTRIDE 36   // 32 + 4: row bank offset 4, q-broadcast -> 2-way max

__global__ __launch_bounds__(256, 2) void sumconv_fused(
    const float* __restrict__ ll, const float* __restrict__ logits,
    float* __restrict__ out) {
  __shared__ float sw[8 * WSTRIDE + 256 * ESTRIDE];  // 13,376 floats = 53,504 B
  float* __restrict__ swW = sw;
  float* __restrict__ swE = sw + 8 * WSTRIDE;

  const int tid = threadIdx.x;
  const int blk = blockIdx.x;
  const int f0 = (blk & 15) * 64;       // f tile [f0, f0+64)
  const int b0 = (blk >> 4) * 4;        // 4 consecutive batch slabs
  const int kkbase = ((f0 >> 5) & 3) * 4;  // in {0, 8}

  // ---- prologue A: softmax of the 8 needed kk slices (exactly 1 per thread) ----
  {
    const int r = tid & 1, kkloc = (tid >> 1) & 7, o = tid >> 4;
    const int kk = kkbase + kkloc;
    // logits float index: o*512 + ci*32 + kk*2 + r
    const float* __restrict__ lg = logits + o * 512 + kk * 2 + r;
    float v[16];
    float m = -1e30f;
#pragma unroll
    for (int ci = 0; ci < 16; ++ci) {
      v[ci] = lg[ci * 32];
      m = fmaxf(m, v[ci]);
    }
    float sum = 0.f;
#pragma unroll
    for (int ci = 0; ci < 16; ++ci) {
      v[ci] = __expf(v[ci] - m);
      sum += v[ci];
    }
    const float inv = 1.0f / sum;
#pragma unroll
    for (int ci = 0; ci < 16; ++ci)
      swW[kkloc * WSTRIDE + ci * 32 + o * 2 + r] = v[ci] * inv;
  }

  // ---- prologue B: stage exp(ll) for 4 b-slabs x 64 rows, coalesced 1KiB/instr ----
#pragma unroll
  for (int j = 0; j < 4; ++j) {
    const float4* __restrict__ src =
        (const float4*)(ll + ((size_t)(b0 + j) * 1024 + f0) * 32);
#pragma unroll
    for (int m2 = 0; m2 < 2; ++m2) {
      const int p = tid + 256 * m2;  // float4 index 0..511 within slab
      const float4 v = src[p];
      const int row = p >> 3, c4 = p & 7;
      *(float4*)(swE + (j * 64 + row) * ESTRIDE + c4 * 4) =
          make_float4(__expf(v.x), __expf(v.y), __expf(v.z), __expf(v.w));
    }
  }
  __syncthreads();

  // ---- main: thread (row, q) computes o in {2q,2q+1,2q+8,2q+9} for 4 rows ----
  const int row = tid >> 2, q = tid & 3;
  const int f = f0 + row;
  const int kk = (((f >> 5) & 3) << 2) | (f & 3);
  const float* __restrict__ wb = swW + (kk & 7) * WSTRIDE + q * 4;

  float Ef[4][32];  // fully static-indexed after unroll (no scratch)
#pragma unroll
  for (int j = 0; j < 4; ++j) {
    const float* __restrict__ eb = swE + (j * 64 + row) * ESTRIDE;
#pragma unroll
    for (int k = 0; k < 8; ++k)
      *(float4*)(&Ef[j][4 * k]) = *(const float4*)(eb + 4 * k);
  }

#pragma unroll
  for (int oo = 0; oo < 2; ++oo) {
    float a[4][4];
#pragma unroll
    for (int j = 0; j < 4; ++j)
      a[j][0] = a[j][1] = a[j][2] = a[j][3] = 0.f;
#pragma unroll
    for (int ci = 0; ci < 16; ++ci) {
      const float4 w = *(const float4*)(wb + ci * 32 + oo * 16);
#pragma unroll
      for (int j = 0; j < 4; ++j) {
        a[j][0] = fmaf(w.x, Ef[j][2 * ci + 0], a[j][0]);
        a[j][1] = fmaf(w.y, Ef[j][2 * ci + 1], a[j][1]);
        a[j][2] = fmaf(w.z, Ef[j][2 * ci + 0], a[j][2]);
        a[j][3] = fmaf(w.w, Ef[j][2 * ci + 1], a[j][3]);
      }
    }
    // o-pair (2q+8oo, 2q+8oo+1) -> output float4 #(q+4oo) of each row
#pragma unroll
    for (int j = 0; j < 4; ++j) {
      const size_t i = (size_t)(b0 + j) * 1024 + f;
      ((float4*)(out + i * 32))[q + 4 * oo] = make_float4(
          __logf(a[j][0]), __logf(a[j][1]), __logf(a[j][2]), __logf(a[j][3]));
    }
  }
}

extern "C" void kernel_launch(void* const* d_in, const int* in_sizes, int n_in,
                              void* d_out, int out_size, void* d_ws, size_t ws_size,
                              hipStream_t stream) {
  const float* ll     = (const float*)d_in[0];
  const float* logits = (const float*)d_in[1];
  float* out = (float*)d_out;
  // 131072 rows / 256 rows-per-block = 512 blocks
  sumconv_fused<<<512, 256, 0, stream>>>(ll, logits, out);
}